// Round 11
// baseline (23844.456 us; speedup 1.0000x reference)
//
#include <hip/hip_runtime.h>

typedef __attribute__((ext_vector_type(8))) short short8;
typedef __attribute__((ext_vector_type(8))) __bf16 bf16x8;
typedef __attribute__((ext_vector_type(4))) float f32x4;

#define GENF 100
#define TCOND 50
#define BATCH 128
#define HID 1024
#define INP 171
#define INPAD 192
#define OUTN 171
#define OUTPAD 176
#define SPLITS 4
#define TILES 64
#define NBLK 256

static __device__ __forceinline__ unsigned short f2bf(float f) {
  unsigned u = __builtin_bit_cast(unsigned, f);
  u += 0x7fffu + ((u >> 16) & 1u);
  return (unsigned short)(u >> 16);
}
static __device__ __forceinline__ float bf2f(unsigned short s) {
  unsigned u = ((unsigned)s) << 16;
  return __builtin_bit_cast(float, u);
}
static __device__ __forceinline__ bf16x8 ld8(const unsigned short* p) {
  short8 v = *reinterpret_cast<const short8*>(p);
  return __builtin_bit_cast(bf16x8, v);
}
static __device__ __forceinline__ float sigm(float x) { return 1.f / (1.f + __expf(-x)); }

// Dependency gate: block waits until monotonic counter >= tgt. Arrivals are
// RELEASE-fenced by producers; one ACQUIRE refreshes this CU's caches.
static __device__ __forceinline__ void gate(unsigned* ctr, int tgt) {
  if (tgt <= 0) return;
  __syncthreads();
  if (threadIdx.x == 0) {
    while ((int)__hip_atomic_load(ctr, __ATOMIC_RELAXED, __HIP_MEMORY_SCOPE_AGENT) < tgt)
      __builtin_amdgcn_s_sleep(4);
    (void)__hip_atomic_load(ctr, __ATOMIC_ACQUIRE, __HIP_MEMORY_SCOPE_AGENT);
  }
  __syncthreads();
}

struct Params {
  const unsigned short* xch; const unsigned short* xcl;
  unsigned short* fxh; unsigned short* fxl;
  const unsigned short* wH[3]; const unsigned short* wL[3];
  const float* bias[3];
  float* c[3];
  unsigned short* hh[3][2]; unsigned short* hl[3][2];
  const unsigned short* wdh; const unsigned short* wdl; const float* bd;
  float* out;
  float* partials;     // 3 layers x SPLITS x BATCH x 4096 f32
  unsigned* counters;  // 3 x TILES
  unsigned* ec;        // ec[0]=+0, ec[1]=+64, ec[2]=+128, dc=+192 (padded lines)
};

// One LSTM layer phase (R10 body): split-K GEMM, 3 rotating LDS bufs, depth-2
// prefetch, counted vmcnt(24); counter-elected finisher does the cell epilogue,
// then RELEASE-bumps this layer's epoch counter.
static __device__ __forceinline__ void layer_phase(
    char* smem, int blk,
    const unsigned short* __restrict__ xh_, const unsigned short* __restrict__ xl_,
    int ldx, int xc,
    const unsigned short* __restrict__ hh_, const unsigned short* __restrict__ hl_,
    const unsigned short* __restrict__ wH, const unsigned short* __restrict__ wL,
    int ldw, int NK,
    const float* __restrict__ bias,
    float* __restrict__ c,
    unsigned short* __restrict__ ohh, unsigned short* __restrict__ ohl,
    float* __restrict__ partials, unsigned* __restrict__ counters,
    unsigned* __restrict__ ecL)
{
  const int t = threadIdx.x;
  const int lane = t & 63, wv = t >> 6;
  const int nt = blk & (TILES - 1), sp = blk >> 6;
  const int n0 = nt * 64 + wv * 16;
  const int nit = NK / SPLITS;  // even
  const int beg = sp * nit;
  const int ns = nit >> 1;

  const int r_row = lane & 15, kg = lane >> 4;
  const int rslot = kg ^ (r_row & 3);
  const int srow = t >> 2;
  const size_t bcol = (size_t)(n0 + r_row) * ldw + kg * 8;

  auto stage1 = [&](char* dst, int ck) {
    const unsigned short *sh, *sl;
    int ld, k0;
    if (ck < xc) { sh = xh_; sl = xl_; ld = ldx; k0 = ck * 32; }
    else { sh = hh_; sl = hl_; ld = HID; k0 = (ck - xc) * 32; }
#pragma unroll
    for (int j = 0; j < 2; ++j) {
      int rowp = j * 64 + srow;
      int slot = (t & 3) ^ (rowp & 3);
      const unsigned short* gh = sh + (size_t)rowp * ld + k0 + slot * 8;
      const unsigned short* gl = sl + (size_t)rowp * ld + k0 + slot * 8;
      char* dh = dst + j * 4096 + wv * 1024;
      char* dl = dst + 8192 + j * 4096 + wv * 1024;
      __builtin_amdgcn_global_load_lds((const __attribute__((address_space(1))) void*)gh,
                                       (__attribute__((address_space(3))) void*)dh, 16, 0, 0);
      __builtin_amdgcn_global_load_lds((const __attribute__((address_space(1))) void*)gl,
                                       (__attribute__((address_space(3))) void*)dl, 16, 0, 0);
    }
  };

  f32x4 zz = {0.f, 0.f, 0.f, 0.f};
  f32x4 acc[8] = {zz, zz, zz, zz, zz, zz, zz, zz};

  char* bA = smem;
  char* bB = smem + 32768;
  char* bC = smem + 65536;

  stage1(bA, beg);
  stage1(bA + 16384, beg + 1);
  bf16x8 b0h0 = ld8(wH + bcol + (size_t)(beg + 0) * 32);
  bf16x8 b0l0 = ld8(wL + bcol + (size_t)(beg + 0) * 32);
  bf16x8 b0h1 = ld8(wH + bcol + (size_t)(beg + 1) * 32);
  bf16x8 b0l1 = ld8(wL + bcol + (size_t)(beg + 1) * 32);
  __builtin_amdgcn_sched_barrier(0);
  stage1(bB, beg + 2);
  stage1(bB + 16384, beg + 3);
  bf16x8 b1h0 = ld8(wH + bcol + (size_t)(beg + 2) * 32);
  bf16x8 b1l0 = ld8(wL + bcol + (size_t)(beg + 2) * 32);
  bf16x8 b1h1 = ld8(wH + bcol + (size_t)(beg + 3) * 32);
  bf16x8 b1l1 = ld8(wL + bcol + (size_t)(beg + 3) * 32);
  __builtin_amdgcn_sched_barrier(0);

  for (int i = 0; i < ns; ++i) {
    int ck = beg + 2 * i + 4;
    if (ck >= beg + nit) ck = beg;  // clamped junk tail (uniform counts, unused)
    stage1(bC, ck);
    stage1(bC + 16384, ck + 1);
    bf16x8 b2h0 = ld8(wH + bcol + (size_t)ck * 32);
    bf16x8 b2l0 = ld8(wL + bcol + (size_t)ck * 32);
    bf16x8 b2h1 = ld8(wH + bcol + (size_t)(ck + 1) * 32);
    bf16x8 b2l1 = ld8(wL + bcol + (size_t)(ck + 1) * 32);
    __builtin_amdgcn_sched_barrier(0);

    asm volatile("s_waitcnt vmcnt(24)" ::: "memory");
    __builtin_amdgcn_s_barrier();
    __builtin_amdgcn_sched_barrier(0);

#pragma unroll
    for (int ch = 0; ch < 2; ++ch) {
      bf16x8 ah[8], al[8];
#pragma unroll
      for (int rg = 0; rg < 8; ++rg) {
        int ro = ch * 16384 + (rg * 16 + r_row) * 64 + rslot * 16;
        ah[rg] = *reinterpret_cast<const bf16x8*>(bA + ro);
        al[rg] = *reinterpret_cast<const bf16x8*>(bA + ro + 8192);
      }
      bf16x8 BH = ch ? b0h1 : b0h0;
      bf16x8 BL = ch ? b0l1 : b0l0;
#pragma unroll
      for (int rg = 0; rg < 8; ++rg)
        acc[rg] = __builtin_amdgcn_mfma_f32_16x16x32_bf16(ah[rg], BH, acc[rg], 0, 0, 0);
#pragma unroll
      for (int rg = 0; rg < 8; ++rg)
        acc[rg] = __builtin_amdgcn_mfma_f32_16x16x32_bf16(al[rg], BH, acc[rg], 0, 0, 0);
#pragma unroll
      for (int rg = 0; rg < 8; ++rg)
        acc[rg] = __builtin_amdgcn_mfma_f32_16x16x32_bf16(ah[rg], BL, acc[rg], 0, 0, 0);
    }
    __builtin_amdgcn_sched_barrier(0);
    __builtin_amdgcn_s_barrier();

    char* tmp = bA; bA = bB; bB = bC; bC = tmp;
    b0h0 = b1h0; b0l0 = b1l0; b0h1 = b1h1; b0l1 = b1l1;
    b1h0 = b2h0; b1l0 = b2l0; b1h1 = b2h1; b1l1 = b2l1;
  }

  {
    float* pb = partials + (size_t)sp * (BATCH * 4096);
    const int cn = n0 + r_row;
    const int mb = kg * 4;
#pragma unroll
    for (int rg = 0; rg < 8; ++rg)
#pragma unroll
      for (int r = 0; r < 4; ++r)
        pb[(size_t)(rg * 16 + mb + r) * 4096 + cn] = acc[rg][r];
  }

  __syncthreads();  // drain stores + junk staging
  __shared__ unsigned oldv;
  if (t == 0)
    oldv = __hip_atomic_fetch_add(&counters[nt], 1u, __ATOMIC_ACQ_REL, __HIP_MEMORY_SCOPE_AGENT);
  __syncthreads();
  if (oldv != SPLITS - 1) return;

  (void)__hip_atomic_load(&counters[nt], __ATOMIC_ACQUIRE, __HIP_MEMORY_SCOPE_AGENT);
  const int fc = t & 15, fm = t >> 4;
  const int nh = nt * 16 + fc;
  const f32x4 bv = *reinterpret_cast<const f32x4*>(&bias[nh * 4]);
#pragma unroll
  for (int p = 0; p < 8; ++p) {
    int m = fm + p * 16;
    size_t gi0 = (size_t)m * 4096 + nh * 4;
    f32x4 s = *reinterpret_cast<const f32x4*>(&partials[gi0]);
#pragma unroll
    for (int q = 1; q < SPLITS; ++q)
      s += *reinterpret_cast<const f32x4*>(&partials[gi0 + (size_t)q * BATCH * 4096]);
    float gi = sigm(s[0] + bv[0]);
    float gf = sigm(s[1] + bv[1]);
    float gg = tanhf(s[2] + bv[2]);
    float go = sigm(s[3] + bv[3]);
    size_t sidx = (size_t)m * HID + nh;
    float cn2 = gf * c[sidx] + gi * gg;
    c[sidx] = cn2;
    float h = go * tanhf(cn2);
    unsigned short h16 = f2bf(h);
    ohh[sidx] = h16;
    ohl[sidx] = f2bf(h - bf2f(h16));
  }
  __syncthreads();  // drain h/c writes before release
  if (t == 0) {
    __hip_atomic_store(&counters[nt], 0u, __ATOMIC_RELAXED, __HIP_MEMORY_SCOPE_AGENT);
    __hip_atomic_fetch_add(ecL, 1u, __ATOMIC_RELEASE, __HIP_MEMORY_SCOPE_AGENT);
  }
}

// Decoder phase: blocks 0..87; RELEASE-bumps dc when done.
static __device__ __forceinline__ void dec_phase(
    char* smem, int blk,
    const unsigned short* __restrict__ hhi, const unsigned short* __restrict__ hlo,
    const unsigned short* __restrict__ wdhi, const unsigned short* __restrict__ wdlo,
    const float* __restrict__ bd, float* __restrict__ outp,
    unsigned short* __restrict__ fxhi, unsigned short* __restrict__ fxlo,
    unsigned* __restrict__ dc)
{
  const int wave = threadIdx.x >> 6, lane = threadIdx.x & 63;
  const int n0 = (blk % 11) * 16;
  const int m0 = (blk / 11) * 16;
  const int row = lane & 15, kg = lane >> 4;
  f32x4 acc = {0.f, 0.f, 0.f, 0.f};
  const unsigned short* pah = hhi + (size_t)(m0 + row) * HID + kg * 8 + wave * 256;
  const unsigned short* pal = hlo + (size_t)(m0 + row) * HID + kg * 8 + wave * 256;
  const unsigned short* pbh = wdhi + (size_t)(n0 + row) * HID + kg * 8 + wave * 256;
  const unsigned short* pbl = wdlo + (size_t)(n0 + row) * HID + kg * 8 + wave * 256;
#pragma unroll
  for (int kk = 0; kk < 8; ++kk) {
    int off2 = kk * 32;
    bf16x8 a1 = ld8(pah + off2), a2 = ld8(pal + off2);
    bf16x8 b1 = ld8(pbh + off2), b2 = ld8(pbl + off2);
    acc = __builtin_amdgcn_mfma_f32_16x16x32_bf16(a1, b1, acc, 0, 0, 0);
    acc = __builtin_amdgcn_mfma_f32_16x16x32_bf16(a2, b1, acc, 0, 0, 0);
    acc = __builtin_amdgcn_mfma_f32_16x16x32_bf16(a1, b2, acc, 0, 0, 0);
  }
  f32x4 (*red)[64] = (f32x4(*)[64])smem;
  if (wave) red[wave][lane] = acc;
  __syncthreads();
  if (wave == 0) {
    acc += red[1][lane];
    acc += red[2][lane];
    acc += red[3][lane];
    const int col = lane & 15, rg = lane >> 4;
#pragma unroll
    for (int r = 0; r < 4; ++r) {
      int m = m0 + rg * 4 + r;
      int n = n0 + col;
      if (n < OUTN) {
        float v = acc[r] + bd[n];
        if (outp) outp[(size_t)m * (GENF * OUTN) + n] = v;
        unsigned short vh = f2bf(v);
        fxhi[(size_t)m * INPAD + n] = vh;
        fxlo[(size_t)m * INPAD + n] = f2bf(v - bf2f(vh));
      }
    }
  }
  __syncthreads();  // drain fx/out writes before release
  if (threadIdx.x == 0)
    __hip_atomic_fetch_add(dc, 1u, __ATOMIC_RELEASE, __HIP_MEMORY_SCOPE_AGENT);
}

// Persistent dataflow kernel: all 150 steps; per-block dependency gates instead
// of grid barriers. Pure own-h splits run ahead; only x-containing splits wait
// on the producer layer -> layers overlap, critical path = x-split chain.
__global__ __launch_bounds__(256) void lstm_persist_k(Params p) {
  __shared__ __align__(16) char smem[98304];
  const int blk = blockIdx.x;
  const int sp = blk >> 6;
  unsigned* ec0 = p.ec;
  unsigned* ec1 = p.ec + 64;
  unsigned* ec2 = p.ec + 128;
  unsigned* dc = p.ec + 192;
  const size_t PSTRIDE = (size_t)SPLITS * BATCH * 4096;

  for (int s = 0; s < TCOND + GENF; ++s) {
    const int pp = s & 1, np = pp ^ 1;
    // ---- layer 0 ----
    {
      const unsigned short *xh, *xl;
      if (s < TCOND) {
        xh = p.xch + (size_t)s * BATCH * INPAD;
        xl = p.xcl + (size_t)s * BATCH * INPAD;
      } else {
        xh = p.fxh;
        xl = p.fxl;
      }
      gate(ec0, 64 * s);                 // own-h prev step + counter/partials WAR
      gate(ec1, 64 * (s - 1));           // WAR: L1 readers of h0 buffer
      if (sp == 0 && s >= TCOND) gate(dc, 88 * (s - TCOND + 1));  // x = dec(s-1)
      layer_phase(smem, blk, xh, xl, INPAD, INPAD / 32, p.hh[0][pp], p.hl[0][pp],
                  p.wH[0], p.wL[0], 1280, 40, p.bias[0], p.c[0],
                  p.hh[0][np], p.hl[0][np], p.partials, p.counters, ec0);
    }
    // ---- layer 1 ----
    gate(ec1, 64 * s);
    gate(ec2, 64 * (s - 1));
    if (sp < 2) gate(ec0, 64 * (s + 1));  // x = h0 this step
    layer_phase(smem, blk, p.hh[0][np], p.hl[0][np], HID, HID / 32,
                p.hh[1][pp], p.hl[1][pp], p.wH[1], p.wL[1], 2 * HID, 64,
                p.bias[1], p.c[1], p.hh[1][np], p.hl[1][np],
                p.partials + PSTRIDE, p.counters + TILES, ec1);
    // ---- layer 2 ----
    gate(ec2, 64 * s);
    if (s >= TCOND + 1) gate(dc, 88 * (s - TCOND));  // WAR: dec readers of h2 buffer
    if (sp < 2) gate(ec1, 64 * (s + 1));  // x = h1 this step
    layer_phase(smem, blk, p.hh[1][np], p.hl[1][np], HID, HID / 32,
                p.hh[2][pp], p.hl[2][pp], p.wH[2], p.wL[2], 2 * HID, 64,
                p.bias[2], p.c[2], p.hh[2][np], p.hl[2][np],
                p.partials + 2 * PSTRIDE, p.counters + 2 * TILES, ec2);
    // ---- decoder ----
    if (s >= TCOND - 1 && blk < 88) {
      gate(ec2, 64 * (s + 1));
      float* outp = (s >= TCOND) ? p.out + (size_t)(s - TCOND) * OUTN : (float*)0;
      dec_phase(smem, blk, p.hh[2][np], p.hl[2][np], p.wdh, p.wdl, p.bd,
                outp, p.fxh, p.fxl, dc);
    }
  }
}

// ---- prep kernels ----
__global__ void cvt_w_k(const float* __restrict__ src, unsigned short* __restrict__ hi,
                        unsigned short* __restrict__ lo, int C, int Cpad, int co, int dstride)
{
  int idx = blockIdx.x * 256 + threadIdx.x;
  if (idx >= 4096 * Cpad) return;
  int r = idx / Cpad, cc = idx - r * Cpad;
  float v = (cc < C) ? src[(size_t)r * C + cc] : 0.f;
  int rp = (r & 1023) * 4 + (r >> 10);
  size_t di = (size_t)rp * dstride + co + cc;
  unsigned short h = f2bf(v);
  hi[di] = h;
  lo[di] = f2bf(v - bf2f(h));
}

__global__ void cvt_hilo_k(const float* __restrict__ src, unsigned short* __restrict__ hi,
                           unsigned short* __restrict__ lo, int R, int C, int Rp, int Cp)
{
  int idx = blockIdx.x * 256 + threadIdx.x;
  if (idx >= Rp * Cp) return;
  int r = idx / Cp, c2 = idx - r * Cp;
  float v = (r < R && c2 < C) ? src[(size_t)r * C + c2] : 0.f;
  unsigned short h = f2bf(v);
  hi[idx] = h;
  lo[idx] = f2bf(v - bf2f(h));
}

__global__ void bias_perm_k(const float* __restrict__ a, const float* __restrict__ b,
                            float* __restrict__ dst)
{
  int i = blockIdx.x * 256 + threadIdx.x;
  if (i < 4096) dst[(i & 1023) * 4 + (i >> 10)] = a[i] + b[i];
}

__global__ void biaspad_k(const float* __restrict__ a, float* __restrict__ dst, int n, int np)
{
  int i = blockIdx.x * 256 + threadIdx.x;
  if (i < np) dst[i] = (i < n) ? a[i] : 0.f;
}

__global__ void xcond_k(const float* __restrict__ seq, unsigned short* __restrict__ xhi,
                        unsigned short* __restrict__ xlo)
{
  int idx = blockIdx.x * 256 + threadIdx.x;
  const int total = TCOND * BATCH * INPAD;
  if (idx >= total) return;
  int t = idx / (BATCH * INPAD);
  int rem = idx - t * (BATCH * INPAD);
  int b = rem / INPAD;
  int k = rem - b * INPAD;
  float v = (k < INP) ? seq[((size_t)b * TCOND + t) * INP + k] : 0.f;
  unsigned short h = f2bf(v);
  xhi[idx] = h;
  xlo[idx] = f2bf(v - bf2f(h));
}

extern "C" void kernel_launch(void* const* d_in, const int* in_sizes, int n_in,
                              void* d_out, int out_size, void* d_ws, size_t ws_size,
                              hipStream_t stream)
{
  (void)in_sizes; (void)n_in; (void)out_size;
  const float* seq   = (const float*)d_in[0];
  const float* w_ih1 = (const float*)d_in[2];
  const float* w_hh1 = (const float*)d_in[3];
  const float* b_ih1 = (const float*)d_in[4];
  const float* b_hh1 = (const float*)d_in[5];
  const float* w_ih2 = (const float*)d_in[6];
  const float* w_hh2 = (const float*)d_in[7];
  const float* b_ih2 = (const float*)d_in[8];
  const float* b_hh2 = (const float*)d_in[9];
  const float* w_ih3 = (const float*)d_in[10];
  const float* w_hh3 = (const float*)d_in[11];
  const float* b_ih3 = (const float*)d_in[12];
  const float* b_hh3 = (const float*)d_in[13];
  const float* w_dec = (const float*)d_in[14];
  const float* b_dec = (const float*)d_in[15];
  float* out = (float*)d_out;

  char* ws = (char*)d_ws;
  size_t off = 0;
  auto alloc = [&](size_t bytes) -> char* {
    off = (off + 255) & ~(size_t)255;
    char* p = ws + off;
    off += bytes;
    return p;
  };
  auto us = [&](size_t n) { return (unsigned short*)alloc(n * 2); };
  auto fl = [&](size_t n) { return (float*)alloc(n * 4); };

  const int K1P = 1280;        // padded: 192 + 1024 = 1216 -> 1280 (NK=40)
  const int K2 = 2 * HID;      // 2048 (NK=64)
  unsigned short *W1h = us((size_t)4096 * K1P), *W1l = us((size_t)4096 * K1P);
  unsigned short *W2h = us((size_t)4096 * K2), *W2l = us((size_t)4096 * K2);
  unsigned short *W3h = us((size_t)4096 * K2), *W3l = us((size_t)4096 * K2);
  unsigned short *wdh = us((size_t)OUTPAD * HID), *wdl = us((size_t)OUTPAD * HID);
  float *b1 = fl(4096), *b2 = fl(4096), *b3 = fl(4096), *bd = fl(OUTPAD);
  unsigned short *xch = us((size_t)TCOND * BATCH * INPAD), *xcl = us((size_t)TCOND * BATCH * INPAD);
  float* partials = fl((size_t)3 * SPLITS * BATCH * 4096);

  size_t state_beg = (off + 255) & ~(size_t)255;
  float *c0 = fl((size_t)BATCH * HID), *c1 = fl((size_t)BATCH * HID), *c2 = fl((size_t)BATCH * HID);
  unsigned short* Hh[3][2];
  unsigned short* Hl[3][2];
  for (int L = 0; L < 3; ++L)
    for (int p = 0; p < 2; ++p) {
      Hh[L][p] = us((size_t)BATCH * HID);
      if (L == 0) alloc(1024);  // zero guard: K1 pad chunks read past last h row
      Hl[L][p] = us((size_t)BATCH * HID);
      if (L == 0) alloc(1024);
    }
  unsigned short *fxh = us((size_t)BATCH * INPAD), *fxl = us((size_t)BATCH * INPAD);
  unsigned* counters = (unsigned*)alloc(3 * TILES * 4);
  unsigned* ec = (unsigned*)alloc(256 * 4);  // ec0/ec1/ec2/dc on 256B-spaced lines
  size_t state_end = off;

  if (off > ws_size) return;  // scratch too small; fail visibly

  hipMemsetAsync(ws + state_beg, 0, state_end - state_beg, stream);
  hipMemsetAsync(W1h, 0, (size_t)4096 * K1P * 2, stream);
  hipMemsetAsync(W1l, 0, (size_t)4096 * K1P * 2, stream);

  // ---- weight / input prep ----
  auto cw = [&](const float* s, unsigned short* h, unsigned short* l, int C, int Cpad, int co, int ds2) {
    int n = 4096 * Cpad;
    cvt_w_k<<<(n + 255) / 256, 256, 0, stream>>>(s, h, l, C, Cpad, co, ds2);
  };
  cw(w_ih1, W1h, W1l, INP, INPAD, 0, K1P);
  cw(w_hh1, W1h, W1l, HID, HID, INPAD, K1P);
  cw(w_ih2, W2h, W2l, HID, HID, 0, K2);
  cw(w_hh2, W2h, W2l, HID, HID, HID, K2);
  cw(w_ih3, W3h, W3l, HID, HID, 0, K2);
  cw(w_hh3, W3h, W3l, HID, HID, HID, K2);
  {
    int n = OUTPAD * HID;
    cvt_hilo_k<<<(n + 255) / 256, 256, 0, stream>>>(w_dec, wdh, wdl, OUTN, HID, OUTPAD, HID);
  }
  bias_perm_k<<<16, 256, 0, stream>>>(b_ih1, b_hh1, b1);
  bias_perm_k<<<16, 256, 0, stream>>>(b_ih2, b_hh2, b2);
  bias_perm_k<<<16, 256, 0, stream>>>(b_ih3, b_hh3, b3);
  biaspad_k<<<1, 256, 0, stream>>>(b_dec, bd, OUTN, OUTPAD);
  {
    int n = TCOND * BATCH * INPAD;
    xcond_k<<<(n + 255) / 256, 256, 0, stream>>>(seq, xch, xcl);
  }

  // ---- single persistent dataflow kernel: all 150 steps ----
  Params P;
  P.xch = xch; P.xcl = xcl; P.fxh = fxh; P.fxl = fxl;
  P.wH[0] = W1h; P.wL[0] = W1l;
  P.wH[1] = W2h; P.wL[1] = W2l;
  P.wH[2] = W3h; P.wL[2] = W3l;
  P.bias[0] = b1; P.bias[1] = b2; P.bias[2] = b3;
  P.c[0] = c0; P.c[1] = c1; P.c[2] = c2;
  for (int L = 0; L < 3; ++L)
    for (int p2 = 0; p2 < 2; ++p2) {
      P.hh[L][p2] = Hh[L][p2];
      P.hl[L][p2] = Hl[L][p2];
    }
  P.wdh = wdh; P.wdl = wdl; P.bd = bd;
  P.out = out;
  P.partials = partials;
  P.counters = counters;
  P.ec = ec;
  lstm_persist_k<<<NBLK, 256, 0, stream>>>(P);
}

// Round 12
// 14096.283 us; speedup vs baseline: 1.6915x; 1.6915x over previous
//
#include <hip/hip_runtime.h>

typedef __attribute__((ext_vector_type(8))) short short8;
typedef __attribute__((ext_vector_type(8))) _Float16 f16x8;
typedef __attribute__((ext_vector_type(4))) float f32x4;

#define GENF 100
#define TCOND 50
#define BATCH 128
#define HID 1024
#define INP 171
#define INPAD 192
#define OUTN 171
#define OUTPAD 176
#define SPLITS 4
#define TILES 64

static __device__ __forceinline__ unsigned short f2h(float f) {
  _Float16 h = (_Float16)f;  // round-to-nearest-even
  return __builtin_bit_cast(unsigned short, h);
}
static __device__ __forceinline__ float h2f(unsigned short s) {
  return (float)__builtin_bit_cast(_Float16, s);
}
static __device__ __forceinline__ f16x8 ld8(const unsigned short* p) {
  short8 v = *reinterpret_cast<const short8*>(p);
  return __builtin_bit_cast(f16x8, v);
}
static __device__ __forceinline__ float sigm(float x) { return 1.f / (1.f + __expf(-x)); }

// Fused LSTM layer: split-K GEMM + counter-elected finisher cell epilogue.
// fp16x2: A = ahi + alo (fp16 pair ~ fp32), W = single fp16 -> 2 MFMA products
// per chunk, HALF the weight stream of bf16x3.
// K-loop: 3 rotating LDS bufs (2 chunks = 32KB each), depth-2 prefetch, counted
// s_waitcnt vmcnt(20) (= 2 supers x 10 VMEM ops/wave in flight) + raw s_barrier.
// W layout: [4096 perm rows (nh*4+g)][ldw] fp16, k-space = x-cols || h-cols.
// Grid: TILES*SPLITS=256 blocks x 256 thr. nit=NK/SPLITS must be even, >=4.
__global__ __launch_bounds__(256) void lstm_gemm_k(
    const unsigned short* __restrict__ xh_, const unsigned short* __restrict__ xl_,
    int ldx, int xc,
    const unsigned short* __restrict__ hh_, const unsigned short* __restrict__ hl_,
    const unsigned short* __restrict__ wH,
    int ldw, int NK,
    const float* __restrict__ bias,
    float* __restrict__ c,
    unsigned short* __restrict__ ohh, unsigned short* __restrict__ ohl,
    float* __restrict__ partials, unsigned* __restrict__ counters)
{
  __shared__ __align__(16) char smem[98304];  // 3 bufs x 2 chunks x (hi 8K + lo 8K)
  const int t = threadIdx.x;
  const int lane = t & 63, wv = t >> 6;
  const int nt = blockIdx.x & (TILES - 1), sp = blockIdx.x >> 6;
  const int n0 = nt * 64 + wv * 16;  // wave's 16-col strip (perm space)
  const int nit = NK / SPLITS;       // even
  const int beg = sp * nit;
  const int ns = nit >> 1;           // super-iters (2 chunks each)

  const int r_row = lane & 15, kg = lane >> 4;
  const int rslot = kg ^ (r_row & 3);  // swizzled 16B slot for ds_read
  const int srow = t >> 2;             // staging row (+ j*64)
  const size_t bcol = (size_t)(n0 + r_row) * ldw + kg * 8;

  // stage one 32-col k-chunk (A hi/lo, 128 rows) into 16KB at dst
  auto stage1 = [&](char* dst, int ck) {
    const unsigned short *sh, *sl;
    int ld, k0;
    if (ck < xc) { sh = xh_; sl = xl_; ld = ldx; k0 = ck * 32; }
    else { sh = hh_; sl = hl_; ld = HID; k0 = (ck - xc) * 32; }
#pragma unroll
    for (int j = 0; j < 2; ++j) {
      int rowp = j * 64 + srow;
      int slot = (t & 3) ^ (rowp & 3);  // inverse-swizzled global source
      const unsigned short* gh = sh + (size_t)rowp * ld + k0 + slot * 8;
      const unsigned short* gl = sl + (size_t)rowp * ld + k0 + slot * 8;
      char* dh = dst + j * 4096 + wv * 1024;
      char* dl = dst + 8192 + j * 4096 + wv * 1024;
      __builtin_amdgcn_global_load_lds((const __attribute__((address_space(1))) void*)gh,
                                       (__attribute__((address_space(3))) void*)dh, 16, 0, 0);
      __builtin_amdgcn_global_load_lds((const __attribute__((address_space(1))) void*)gl,
                                       (__attribute__((address_space(3))) void*)dl, 16, 0, 0);
    }
  };

  f32x4 zz = {0.f, 0.f, 0.f, 0.f};
  f32x4 acc[8] = {zz, zz, zz, zz, zz, zz, zz, zz};

  char* bA = smem;
  char* bB = smem + 32768;
  char* bC = smem + 65536;

  // prologue: supers 0 and 1 in flight (10 VMEM ops/wave each, issue-grouped)
  stage1(bA, beg);
  stage1(bA + 16384, beg + 1);
  f16x8 b0h0 = ld8(wH + bcol + (size_t)(beg + 0) * 32);
  f16x8 b0h1 = ld8(wH + bcol + (size_t)(beg + 1) * 32);
  __builtin_amdgcn_sched_barrier(0);
  stage1(bB, beg + 2);
  stage1(bB + 16384, beg + 3);
  f16x8 b1h0 = ld8(wH + bcol + (size_t)(beg + 2) * 32);
  f16x8 b1h1 = ld8(wH + bcol + (size_t)(beg + 3) * 32);
  __builtin_amdgcn_sched_barrier(0);

  for (int i = 0; i < ns; ++i) {
    // issue super i+2 (clamped to beg on tail iters: uniform counts, junk unused)
    int ck = beg + 2 * i + 4;
    if (ck >= beg + nit) ck = beg;
    stage1(bC, ck);
    stage1(bC + 16384, ck + 1);
    f16x8 b2h0 = ld8(wH + bcol + (size_t)ck * 32);
    f16x8 b2h1 = ld8(wH + bcol + (size_t)(ck + 1) * 32);
    __builtin_amdgcn_sched_barrier(0);

    // wait: super i retired (20 = supers i+1, i+2 stay in flight)
    asm volatile("s_waitcnt vmcnt(20)" ::: "memory");
    __builtin_amdgcn_s_barrier();
    __builtin_amdgcn_sched_barrier(0);

#pragma unroll
    for (int ch = 0; ch < 2; ++ch) {
      f16x8 ah[8], al[8];
#pragma unroll
      for (int rg = 0; rg < 8; ++rg) {
        int ro = ch * 16384 + (rg * 16 + r_row) * 64 + rslot * 16;
        ah[rg] = *reinterpret_cast<const f16x8*>(bA + ro);
        al[rg] = *reinterpret_cast<const f16x8*>(bA + ro + 8192);
      }
      f16x8 BH = ch ? b0h1 : b0h0;
#pragma unroll
      for (int rg = 0; rg < 8; ++rg)
        acc[rg] = __builtin_amdgcn_mfma_f32_16x16x32_f16(ah[rg], BH, acc[rg], 0, 0, 0);
#pragma unroll
      for (int rg = 0; rg < 8; ++rg)
        acc[rg] = __builtin_amdgcn_mfma_f32_16x16x32_f16(al[rg], BH, acc[rg], 0, 0, 0);
    }
    __builtin_amdgcn_sched_barrier(0);
    __builtin_amdgcn_s_barrier();  // all waves done reading bA before it's restaged

    // rotate buffers + B fragments (named regs, no runtime indexing)
    char* tmp = bA; bA = bB; bB = bC; bC = tmp;
    b0h0 = b1h0; b0h1 = b1h1;
    b1h0 = b2h0; b1h1 = b2h1;
  }

  // ---- store split partials (plain f32 stores) ----
  {
    float* pb = partials + (size_t)sp * (BATCH * 4096);
    const int cn = n0 + r_row;
    const int mb = kg * 4;
#pragma unroll
    for (int rg = 0; rg < 8; ++rg)
#pragma unroll
      for (int r = 0; r < 4; ++r)
        pb[(size_t)(rg * 16 + mb + r) * 4096 + cn] = acc[rg][r];
  }

  __syncthreads();  // drain stores (and clamped junk loads)
  __shared__ unsigned oldv;
  if (t == 0)
    oldv = __hip_atomic_fetch_add(&counters[nt], 1u, __ATOMIC_ACQ_REL, __HIP_MEMORY_SCOPE_AGENT);
  __syncthreads();
  if (oldv != SPLITS - 1) return;

  // ---- finisher: reduce splits + LSTM cell for this tile's 16 hid cols ----
  (void)__hip_atomic_load(&counters[nt], __ATOMIC_ACQUIRE, __HIP_MEMORY_SCOPE_AGENT);
  const int fc = t & 15, fm = t >> 4;
  const int nh = nt * 16 + fc;
  const f32x4 bv = *reinterpret_cast<const f32x4*>(&bias[nh * 4]);
#pragma unroll
  for (int p = 0; p < 8; ++p) {
    int m = fm + p * 16;
    size_t gi0 = (size_t)m * 4096 + nh * 4;
    f32x4 s = *reinterpret_cast<const f32x4*>(&partials[gi0]);
#pragma unroll
    for (int q = 1; q < SPLITS; ++q)
      s += *reinterpret_cast<const f32x4*>(&partials[gi0 + (size_t)q * BATCH * 4096]);
    float gi = sigm(s[0] + bv[0]);
    float gf = sigm(s[1] + bv[1]);
    float gg = tanhf(s[2] + bv[2]);
    float go = sigm(s[3] + bv[3]);
    size_t sidx = (size_t)m * HID + nh;
    float cn2 = gf * c[sidx] + gi * gg;
    c[sidx] = cn2;
    float h = go * tanhf(cn2);
    unsigned short h16 = f2h(h);
    ohh[sidx] = h16;
    ohl[sidx] = f2h(h - h2f(h16));
  }
  __syncthreads();
  if (t == 0)
    __hip_atomic_store(&counters[nt], 0u, __ATOMIC_RELAXED, __HIP_MEMORY_SCOPE_AGENT);
}

// Decoder: out = h2 @ w_dec^T + b_dec. 4 waves split K, LDS reduce. fp16x2.
__global__ __launch_bounds__(256) void dec_k(
    const unsigned short* __restrict__ hhi, const unsigned short* __restrict__ hlo,
    const unsigned short* __restrict__ wdh,
    const float* __restrict__ bd,
    float* __restrict__ outp,
    unsigned short* __restrict__ fxhi, unsigned short* __restrict__ fxlo)
{
  const int wave = threadIdx.x >> 6, lane = threadIdx.x & 63;
  const int n0 = ((int)blockIdx.x % 11) * 16;
  const int m0 = ((int)blockIdx.x / 11) * 16;
  const int row = lane & 15, kg = lane >> 4;
  f32x4 acc = {0.f, 0.f, 0.f, 0.f};
  const unsigned short* pah = hhi + (size_t)(m0 + row) * HID + kg * 8 + wave * 256;
  const unsigned short* pal = hlo + (size_t)(m0 + row) * HID + kg * 8 + wave * 256;
  const unsigned short* pbh = wdh + (size_t)(n0 + row) * HID + kg * 8 + wave * 256;
#pragma unroll
  for (int kk = 0; kk < 8; ++kk) {
    int off = kk * 32;
    f16x8 a1 = ld8(pah + off), a2 = ld8(pal + off);
    f16x8 b1 = ld8(pbh + off);
    acc = __builtin_amdgcn_mfma_f32_16x16x32_f16(a1, b1, acc, 0, 0, 0);
    acc = __builtin_amdgcn_mfma_f32_16x16x32_f16(a2, b1, acc, 0, 0, 0);
  }
  __shared__ f32x4 red[4][64];
  if (wave) red[wave][lane] = acc;
  __syncthreads();
  if (wave == 0) {
    acc += red[1][lane];
    acc += red[2][lane];
    acc += red[3][lane];
    const int col = lane & 15, rg = lane >> 4;
#pragma unroll
    for (int r = 0; r < 4; ++r) {
      int m = m0 + rg * 4 + r;
      int n = n0 + col;
      if (n < OUTN) {
        float v = acc[r] + bd[n];
        if (outp) outp[(size_t)m * (GENF * OUTN) + n] = v;
        unsigned short vh = f2h(v);
        fxhi[(size_t)m * INPAD + n] = vh;
        fxlo[(size_t)m * INPAD + n] = f2h(v - h2f(vh));
      }
    }
  }
}

// ---- prep kernels ----
// LSTM weight: src [4096 gate-major][C] f32 -> dst rows permuted (nh*4+g), cols at
// [co, co+Cpad) of a [4096][dstride] fp16 buffer; cols C..Cpad-1 zeroed.
__global__ void cvt_w_k(const float* __restrict__ src, unsigned short* __restrict__ w16,
                        int C, int Cpad, int co, int dstride)
{
  int idx = blockIdx.x * 256 + threadIdx.x;
  if (idx >= 4096 * Cpad) return;
  int r = idx / Cpad, cc = idx - r * Cpad;
  float v = (cc < C) ? src[(size_t)r * C + cc] : 0.f;
  int rp = (r & 1023) * 4 + (r >> 10);
  w16[(size_t)rp * dstride + co + cc] = f2h(v);
}

// dec weight: no perm, pad rows to Rp. single fp16.
__global__ void cvt_wd_k(const float* __restrict__ src, unsigned short* __restrict__ w16,
                         int R, int C, int Rp, int Cp)
{
  int idx = blockIdx.x * 256 + threadIdx.x;
  if (idx >= Rp * Cp) return;
  int r = idx / Cp, c2 = idx - r * Cp;
  float v = (r < R && c2 < C) ? src[(size_t)r * C + c2] : 0.f;
  w16[idx] = f2h(v);
}

__global__ void bias_perm_k(const float* __restrict__ a, const float* __restrict__ b,
                            float* __restrict__ dst)
{
  int i = blockIdx.x * 256 + threadIdx.x;
  if (i < 4096) dst[(i & 1023) * 4 + (i >> 10)] = a[i] + b[i];
}

__global__ void biaspad_k(const float* __restrict__ a, float* __restrict__ dst, int n, int np)
{
  int i = blockIdx.x * 256 + threadIdx.x;
  if (i < np) dst[i] = (i < n) ? a[i] : 0.f;
}

// initial_seq [B][T][IN] fp32 -> xcond hi/lo [T][B][INPAD] fp16 (zero-padded cols)
__global__ void xcond_k(const float* __restrict__ seq, unsigned short* __restrict__ xhi,
                        unsigned short* __restrict__ xlo)
{
  int idx = blockIdx.x * 256 + threadIdx.x;
  const int total = TCOND * BATCH * INPAD;
  if (idx >= total) return;
  int t = idx / (BATCH * INPAD);
  int rem = idx - t * (BATCH * INPAD);
  int b = rem / INPAD;
  int k = rem - b * INPAD;
  float v = (k < INP) ? seq[((size_t)b * TCOND + t) * INP + k] : 0.f;
  unsigned short h = f2h(v);
  xhi[idx] = h;
  xlo[idx] = f2h(v - h2f(h));
}

extern "C" void kernel_launch(void* const* d_in, const int* in_sizes, int n_in,
                              void* d_out, int out_size, void* d_ws, size_t ws_size,
                              hipStream_t stream)
{
  (void)in_sizes; (void)n_in; (void)out_size;
  const float* seq   = (const float*)d_in[0];
  const float* w_ih1 = (const float*)d_in[2];
  const float* w_hh1 = (const float*)d_in[3];
  const float* b_ih1 = (const float*)d_in[4];
  const float* b_hh1 = (const float*)d_in[5];
  const float* w_ih2 = (const float*)d_in[6];
  const float* w_hh2 = (const float*)d_in[7];
  const float* b_ih2 = (const float*)d_in[8];
  const float* b_hh2 = (const float*)d_in[9];
  const float* w_ih3 = (const float*)d_in[10];
  const float* w_hh3 = (const float*)d_in[11];
  const float* b_ih3 = (const float*)d_in[12];
  const float* b_hh3 = (const float*)d_in[13];
  const float* w_dec = (const float*)d_in[14];
  const float* b_dec = (const float*)d_in[15];
  float* out = (float*)d_out;

  char* ws = (char*)d_ws;
  size_t off = 0;
  auto alloc = [&](size_t bytes) -> char* {
    off = (off + 255) & ~(size_t)255;
    char* p = ws + off;
    off += bytes;
    return p;
  };
  auto us = [&](size_t n) { return (unsigned short*)alloc(n * 2); };
  auto fl = [&](size_t n) { return (float*)alloc(n * 4); };

  const int K1P = 1280;        // padded: INPAD(192) + HID(1024) = 1216 -> 1280 (NK=40)
  const int K2 = 2 * HID;      // 2048 (NK=64)
  unsigned short *W1 = us((size_t)4096 * K1P);
  unsigned short *W2 = us((size_t)4096 * K2);
  unsigned short *W3 = us((size_t)4096 * K2);
  unsigned short *wd = us((size_t)OUTPAD * HID);
  float *b1 = fl(4096), *b2 = fl(4096), *b3 = fl(4096), *bd = fl(OUTPAD);
  unsigned short *xch = us((size_t)TCOND * BATCH * INPAD), *xcl = us((size_t)TCOND * BATCH * INPAD);
  float* partials = fl((size_t)SPLITS * BATCH * 4096);

  size_t state_beg = (off + 255) & ~(size_t)255;
  float *c0 = fl((size_t)BATCH * HID), *c1 = fl((size_t)BATCH * HID), *c2 = fl((size_t)BATCH * HID);
  unsigned short* Hh[3][2];
  unsigned short* Hl[3][2];
  for (int L = 0; L < 3; ++L)
    for (int p = 0; p < 2; ++p) {
      Hh[L][p] = us((size_t)BATCH * HID);
      Hl[L][p] = us((size_t)BATCH * HID);
    }
  unsigned short *fxh = us((size_t)BATCH * INPAD), *fxl = us((size_t)BATCH * INPAD);
  unsigned* counters = (unsigned*)alloc(TILES * 4);
  size_t state_end = off;

  if (off > ws_size) return;  // scratch too small; fail visibly

  hipMemsetAsync(ws + state_beg, 0, state_end - state_beg, stream);
  // zero W1 pad columns (1216..1280) — memset whole W1 before cvt fills real cols
  hipMemsetAsync(W1, 0, (size_t)4096 * K1P * 2, stream);

  // ---- weight / input prep ----
  auto cw = [&](const float* s, unsigned short* w, int C, int Cpad, int co, int ds2) {
    int n = 4096 * Cpad;
    cvt_w_k<<<(n + 255) / 256, 256, 0, stream>>>(s, w, C, Cpad, co, ds2);
  };
  cw(w_ih1, W1, INP, INPAD, 0, K1P);
  cw(w_hh1, W1, HID, HID, INPAD, K1P);
  cw(w_ih2, W2, HID, HID, 0, K2);
  cw(w_hh2, W2, HID, HID, HID, K2);
  cw(w_ih3, W3, HID, HID, 0, K2);
  cw(w_hh3, W3, HID, HID, HID, K2);
  {
    int n = OUTPAD * HID;
    cvt_wd_k<<<(n + 255) / 256, 256, 0, stream>>>(w_dec, wd, OUTN, HID, OUTPAD, HID);
  }
  bias_perm_k<<<16, 256, 0, stream>>>(b_ih1, b_hh1, b1);
  bias_perm_k<<<16, 256, 0, stream>>>(b_ih2, b_hh2, b2);
  bias_perm_k<<<16, 256, 0, stream>>>(b_ih3, b_hh3, b3);
  biaspad_k<<<1, 256, 0, stream>>>(b_dec, bd, OUTN, OUTPAD);
  {
    int n = TCOND * BATCH * INPAD;
    xcond_k<<<(n + 255) / 256, 256, 0, stream>>>(seq, xch, xcl);
  }

  // ---- recurrent loop ----
  for (int s = 0; s < TCOND + GENF; ++s) {
    const unsigned short *xh, *xl;
    if (s < TCOND) {
      xh = xch + (size_t)s * BATCH * INPAD;
      xl = xcl + (size_t)s * BATCH * INPAD;
    } else {
      xh = fxh;
      xl = fxl;
    }
    int pp = s & 1, np = pp ^ 1;
    lstm_gemm_k<<<TILES * SPLITS, 256, 0, stream>>>(xh, xl, INPAD, INPAD / 32,
        Hh[0][pp], Hl[0][pp], W1, K1P, K1P / 32, b1, c0,
        Hh[0][np], Hl[0][np], partials, counters);
    lstm_gemm_k<<<TILES * SPLITS, 256, 0, stream>>>(Hh[0][np], Hl[0][np], HID, HID / 32,
        Hh[1][pp], Hl[1][pp], W2, K2, K2 / 32, b2, c1,
        Hh[1][np], Hl[1][np], partials, counters);
    lstm_gemm_k<<<TILES * SPLITS, 256, 0, stream>>>(Hh[1][np], Hl[1][np], HID, HID / 32,
        Hh[2][pp], Hl[2][pp], W3, K2, K2 / 32, b3, c2,
        Hh[2][np], Hl[2][np], partials, counters);
    if (s == TCOND - 1) {
      dec_k<<<88, 256, 0, stream>>>(Hh[2][np], Hl[2][np], wd, bd,
                                    (float*)nullptr, fxh, fxl);
    } else if (s >= TCOND) {
      dec_k<<<88, 256, 0, stream>>>(Hh[2][np], Hl[2][np], wd, bd,
                                    out + (size_t)(s - TCOND) * OUTN, fxh, fxl);
    }
  }
}